// Round 1
// baseline (449.300 us; speedup 1.0000x reference)
//
#include <hip/hip_runtime.h>
#include <hip/hip_bf16.h>
#include <stdint.h>

typedef __attribute__((ext_vector_type(8))) __bf16 bf16x8;
typedef __attribute__((ext_vector_type(4))) float f32x4;

#define MROWS 8192L
#define NCOLS 4096L
#define KDIM  4096L

#define XQ_BYTES   (MROWS * KDIM * 2)            // 67108864
#define WQ_BYTES   (NCOLS * KDIM * 2)            // 33554432
#define SCAL_OFF   (XQ_BYTES + WQ_BYTES)         // 100663296

// ternary -> bf16 bits: +1 = 0x3F80, -1 = 0xBF80, 0 = 0
__device__ __forceinline__ unsigned short tq_bits(float v, float delta) {
    return v > delta ? (unsigned short)0x3F80
                     : (v < -delta ? (unsigned short)0xBF80 : (unsigned short)0);
}

// ---------------- reduction: sum|x| (blocks 0..511), sum|w| (blocks 512..767) ----
__global__ __launch_bounds__(256) void k_reduce_abs(const float* __restrict__ x,
                                                    const float* __restrict__ w,
                                                    float* __restrict__ partials) {
    __shared__ float sm[256];
    int b = blockIdx.x;
    int t = threadIdx.x;
    const float4* v;
    long base;
    if (b < 512) { v = (const float4*)x; base = (long)b * 16384; }
    else         { v = (const float4*)w; base = (long)(b - 512) * 16384; }
    float s = 0.f;
    for (int i = t; i < 16384; i += 256) {
        float4 q = v[base + i];
        s += fabsf(q.x) + fabsf(q.y) + fabsf(q.z) + fabsf(q.w);
    }
    sm[t] = s;
    __syncthreads();
    for (int off = 128; off > 0; off >>= 1) {
        if (t < off) sm[t] += sm[t + off];
        __syncthreads();
    }
    if (t == 0) partials[b] = sm[0];
}

// ---------------- finalize: double-precision combine, write scalars --------------
__global__ __launch_bounds__(256) void k_finalize(float* __restrict__ scal) {
    const float* partials = scal + 4;
    __shared__ double sm[256];
    int t = threadIdx.x;

    double sx = 0.0;
    for (int i = t; i < 512; i += 256) sx += (double)partials[i];
    sm[t] = sx;
    __syncthreads();
    for (int off = 128; off > 0; off >>= 1) {
        if (t < off) sm[t] += sm[t + off];
        __syncthreads();
    }
    double SX = sm[0];
    __syncthreads();

    double sw = (t < 256) ? (double)partials[512 + t] : 0.0;
    sm[t] = sw;
    __syncthreads();
    for (int off = 128; off > 0; off >>= 1) {
        if (t < off) sm[t] += sm[t + off];
        __syncthreads();
    }
    if (t == 0) {
        float meanx = (float)(SX / 33554432.0);
        float meanw = (float)(sm[0] / 16777216.0);
        scal[0] = 0.1f * meanx;   // delta_x
        scal[1] = 0.05f * meanw;  // delta_w
        scal[2] = meanw;          // alpha
    }
}

// ---------------- ternarize to bf16 {-1,0,1} -------------------------------------
__global__ __launch_bounds__(256) void k_quant(const float* __restrict__ src,
                                               unsigned short* __restrict__ dst,
                                               const float* __restrict__ scal,
                                               int scal_idx, long total4) {
    float delta = scal[scal_idx];
    long i0 = (long)blockIdx.x * 256 + threadIdx.x;
    long stride = (long)gridDim.x * 256;
    const float4* s4 = (const float4*)src;
    ushort4* d4 = (ushort4*)dst;
    for (long i = i0; i < total4; i += stride) {
        float4 q = s4[i];
        ushort4 o;
        o.x = tq_bits(q.x, delta);
        o.y = tq_bits(q.y, delta);
        o.z = tq_bits(q.z, delta);
        o.w = tq_bits(q.w, delta);
        d4[i] = o;
    }
}

// ---------------- GEMM: out = alpha * (Xq @ Wq^T), m97-style 128x128 tile --------
#define GLOAD_LDS16(g, l)                                                             \
    __builtin_amdgcn_global_load_lds((const __attribute__((address_space(1))) void*)(g), \
                                     (__attribute__((address_space(3))) void*)(l),       \
                                     16, 0, 0)

__global__ __launch_bounds__(256) void k_gemm(const unsigned short* __restrict__ Xq,
                                              const unsigned short* __restrict__ Wq,
                                              float* __restrict__ out,
                                              const float* __restrict__ scal) {
    __shared__ __attribute__((aligned(16))) unsigned short As[128 * 32]; // 8 KB
    __shared__ __attribute__((aligned(16))) unsigned short Bs[128 * 32]; // 8 KB

    const float alpha = scal[2];

    // XCD-aware bijective swizzle (2048 blocks, 2048 % 8 == 0)
    int bid = (int)blockIdx.x;
    bid = (bid & 7) * 256 + (bid >> 3);
    int bm = bid >> 5;       // 0..63  (M/128)
    int bn = bid & 31;       // 0..31  (N/128)
    long row0 = (long)bm * 128;
    long col0 = (long)bn * 128;

    int t = threadIdx.x;
    int lane = t & 63;
    int wid = t >> 6;        // 0..3
    int wr = wid >> 1;       // 0..1
    int wc = wid & 1;        // 0..1

    // staging geometry: tile = 128 rows x 32 k (bf16), 512 chunks of 16B
    // chunk c (issue j): c = j*256 + wid*64 + lane -> row = c>>2, kcol = (c&3)*8
    int c0 = wid * 64 + lane;
    int arow0 = c0 >> 2;            // 0..63
    int acol = (c0 & 3) * 8;        // k element offset

    const unsigned short* Ag0 = Xq + (row0 + arow0) * KDIM + acol;
    const unsigned short* Ag1 = Xq + (row0 + arow0 + 64) * KDIM + acol;
    const unsigned short* Bg0 = Wq + (col0 + arow0) * KDIM + acol;
    const unsigned short* Bg1 = Wq + (col0 + arow0 + 64) * KDIM + acol;

    unsigned short* Ald0 = As + wid * 512;          // + lane*16B implicit
    unsigned short* Ald1 = As + 2048 + wid * 512;
    unsigned short* Bld0 = Bs + wid * 512;
    unsigned short* Bld1 = Bs + 2048 + wid * 512;

    f32x4 acc[4][4];
#pragma unroll
    for (int i = 0; i < 4; ++i)
#pragma unroll
        for (int j = 0; j < 4; ++j)
            acc[i][j] = (f32x4){0.f, 0.f, 0.f, 0.f};

    const int kc = (lane >> 4) * 8;   // fragment k offset
    const int fr = lane & 15;         // fragment row (A: m, B: n)

    for (int k0 = 0; k0 < KDIM; k0 += 32) {
        GLOAD_LDS16(Ag0 + k0, Ald0);
        GLOAD_LDS16(Ag1 + k0, Ald1);
        GLOAD_LDS16(Bg0 + k0, Bld0);
        GLOAD_LDS16(Bg1 + k0, Bld1);
        __syncthreads();

        bf16x8 af[4], bf[4];
#pragma unroll
        for (int mi = 0; mi < 4; ++mi) {
            int r = wr * 64 + mi * 16 + fr;
            af[mi] = *(const bf16x8*)&As[r * 32 + kc];
        }
#pragma unroll
        for (int ni = 0; ni < 4; ++ni) {
            int r = wc * 64 + ni * 16 + fr;
            bf[ni] = *(const bf16x8*)&Bs[r * 32 + kc];
        }
#pragma unroll
        for (int mi = 0; mi < 4; ++mi)
#pragma unroll
            for (int ni = 0; ni < 4; ++ni)
                acc[mi][ni] = __builtin_amdgcn_mfma_f32_16x16x32_bf16(
                    af[mi], bf[ni], acc[mi][ni], 0, 0, 0);
        __syncthreads();
    }

    // epilogue: C/D mapping (verified): n = lane&15, m = (lane>>4)*4 + reg
#pragma unroll
    for (int mi = 0; mi < 4; ++mi) {
#pragma unroll
        for (int ni = 0; ni < 4; ++ni) {
            long n = col0 + wc * 64 + ni * 16 + (lane & 15);
            long mbase = row0 + wr * 64 + mi * 16 + (lane >> 4) * 4;
#pragma unroll
            for (int r = 0; r < 4; ++r) {
                out[(mbase + r) * NCOLS + n] = alpha * acc[mi][ni][r];
            }
        }
    }
}

// ---------------- host launch ----------------------------------------------------
extern "C" void kernel_launch(void* const* d_in, const int* in_sizes, int n_in,
                              void* d_out, int out_size, void* d_ws, size_t ws_size,
                              hipStream_t stream) {
    const float* x = (const float*)d_in[0];   // 8192 x 4096 f32
    const float* w = (const float*)d_in[1];   // 4096 x 4096 f32
    float* out = (float*)d_out;               // 8192 x 4096 f32

    uint8_t* ws = (uint8_t*)d_ws;
    unsigned short* Xq = (unsigned short*)ws;                 // bf16 ternary x
    unsigned short* Wq = (unsigned short*)(ws + XQ_BYTES);    // bf16 ternary w
    float* scal = (float*)(ws + SCAL_OFF);                    // [delta_x, delta_w, alpha, pad]
    // partials at scal+4 (768 floats)

    k_reduce_abs<<<768, 256, 0, stream>>>(x, w, scal + 4);
    k_finalize<<<1, 256, 0, stream>>>(scal);
    k_quant<<<4096, 256, 0, stream>>>(x, Xq, scal, 0, MROWS * KDIM / 4);
    k_quant<<<2048, 256, 0, stream>>>(w, Wq, scal, 1, NCOLS * KDIM / 4);
    k_gemm<<<2048, 256, 0, stream>>>(Xq, Wq, out, scal);
}

// Round 2
// 263.281 us; speedup vs baseline: 1.7065x; 1.7065x over previous
//
#include <hip/hip_runtime.h>
#include <hip/hip_bf16.h>
#include <stdint.h>

typedef __attribute__((ext_vector_type(4))) int i32x4;

#define MROWS 8192L
#define NCOLS 4096L
#define KDIM  4096L

#define XQ_BYTES   (MROWS * KDIM)                // 33554432 (i8)
#define WQ_BYTES   (NCOLS * KDIM)                // 16777216 (i8)
#define SCAL_OFF   (XQ_BYTES + WQ_BYTES)

// ternary -> i8 {-1,0,+1}
__device__ __forceinline__ int tq_i8(float v, float delta) {
    return v > delta ? 1 : (v < -delta ? -1 : 0);
}

// ---------------- reduction: sum|x| (blocks 0..511), sum|w| (blocks 512..767) ----
__global__ __launch_bounds__(256) void k_reduce_abs(const float* __restrict__ x,
                                                    const float* __restrict__ w,
                                                    float* __restrict__ partials) {
    __shared__ float sm[256];
    int b = blockIdx.x;
    int t = threadIdx.x;
    const float4* v;
    long base;
    if (b < 512) { v = (const float4*)x; base = (long)b * 16384; }
    else         { v = (const float4*)w; base = (long)(b - 512) * 16384; }
    float s = 0.f;
    for (int i = t; i < 16384; i += 256) {
        float4 q = v[base + i];
        s += fabsf(q.x) + fabsf(q.y) + fabsf(q.z) + fabsf(q.w);
    }
    sm[t] = s;
    __syncthreads();
    for (int off = 128; off > 0; off >>= 1) {
        if (t < off) sm[t] += sm[t + off];
        __syncthreads();
    }
    if (t == 0) partials[b] = sm[0];
}

// ---------------- finalize: double-precision combine, write scalars --------------
__global__ __launch_bounds__(256) void k_finalize(float* __restrict__ scal) {
    const float* partials = scal + 4;
    __shared__ double sm[256];
    int t = threadIdx.x;

    double sx = 0.0;
    for (int i = t; i < 512; i += 256) sx += (double)partials[i];
    sm[t] = sx;
    __syncthreads();
    for (int off = 128; off > 0; off >>= 1) {
        if (t < off) sm[t] += sm[t + off];
        __syncthreads();
    }
    double SX = sm[0];
    __syncthreads();

    double sw = (double)partials[512 + t];
    sm[t] = sw;
    __syncthreads();
    for (int off = 128; off > 0; off >>= 1) {
        if (t < off) sm[t] += sm[t + off];
        __syncthreads();
    }
    if (t == 0) {
        float meanx = (float)(SX / 33554432.0);
        float meanw = (float)(sm[0] / 16777216.0);
        scal[0] = 0.1f * meanx;   // delta_x
        scal[1] = 0.05f * meanw;  // delta_w
        scal[2] = meanw;          // alpha
    }
}

// ---------------- ternarize to i8 {-1,0,1}, 4 floats -> 1 packed word ------------
__global__ __launch_bounds__(256) void k_quant(const float* __restrict__ src,
                                               int* __restrict__ dst,
                                               const float* __restrict__ scal,
                                               int scal_idx, long total4) {
    float delta = scal[scal_idx];
    long i0 = (long)blockIdx.x * 256 + threadIdx.x;
    long stride = (long)gridDim.x * 256;
    const float4* s4 = (const float4*)src;
    for (long i = i0; i < total4; i += stride) {
        float4 q = s4[i];
        int wd = (tq_i8(q.x, delta) & 0xff)
               | ((tq_i8(q.y, delta) & 0xff) << 8)
               | ((tq_i8(q.z, delta) & 0xff) << 16)
               | ((tq_i8(q.w, delta) & 0xff) << 24);
        dst[i] = wd;
    }
}

// ---------------- GEMM: out = alpha * (Xq @ Wq^T), i8 MFMA K=64 ------------------
#define GLOAD_LDS16(g, l)                                                             \
    __builtin_amdgcn_global_load_lds((const __attribute__((address_space(1))) void*)(g), \
                                     (__attribute__((address_space(3))) void*)(l),       \
                                     16, 0, 0)

__global__ __launch_bounds__(256) void k_gemm(const signed char* __restrict__ Xq,
                                              const signed char* __restrict__ Wq,
                                              float* __restrict__ out,
                                              const float* __restrict__ scal) {
    // 128 rows x 64 k-bytes per matrix = 8 KB each
    __shared__ __attribute__((aligned(16))) signed char As[128 * 64];
    __shared__ __attribute__((aligned(16))) signed char Bs[128 * 64];

    const float alpha = scal[2];

    // XCD-aware bijective swizzle (2048 blocks, 2048 % 8 == 0)
    int bid = (int)blockIdx.x;
    bid = (bid & 7) * 256 + (bid >> 3);
    int bm = bid >> 5;       // 0..63  (M/128)
    int bn = bid & 31;       // 0..31  (N/128)
    long row0 = (long)bm * 128;
    long col0 = (long)bn * 128;

    int t = threadIdx.x;
    int lane = t & 63;
    int wid = t >> 6;        // 0..3
    int wr = wid >> 1;       // 0..1
    int wc = wid & 1;        // 0..1

    // staging: tile = 128 rows x 64 bytes, 512 chunks of 16B, 2 issues/matrix
    // chunk c = issue*256 + wid*64 + lane -> row = c>>2, bytecol = (c&3)*16
    int c0 = wid * 64 + lane;
    int arow = c0 >> 2;             // 0..63
    int bcol = (c0 & 3) * 16;       // byte offset in row

    const signed char* Ag0 = Xq + (row0 + arow) * KDIM + bcol;
    const signed char* Ag1 = Xq + (row0 + arow + 64) * KDIM + bcol;
    const signed char* Bg0 = Wq + (col0 + arow) * KDIM + bcol;
    const signed char* Bg1 = Wq + (col0 + arow + 64) * KDIM + bcol;

    signed char* Ald0 = As + wid * 1024;          // + lane*16 implicit
    signed char* Ald1 = As + 4096 + wid * 1024;
    signed char* Bld0 = Bs + wid * 1024;
    signed char* Bld1 = Bs + 4096 + wid * 1024;

    i32x4 acc[4][4];
#pragma unroll
    for (int i = 0; i < 4; ++i)
#pragma unroll
        for (int j = 0; j < 4; ++j)
            acc[i][j] = (i32x4){0, 0, 0, 0};

    const int kc = (lane >> 4) * 16;  // fragment k byte offset (16 i8/lane)
    const int fr = lane & 15;         // fragment row (A: m, B: n)

    for (int k0 = 0; k0 < KDIM; k0 += 64) {
        GLOAD_LDS16(Ag0 + k0, Ald0);
        GLOAD_LDS16(Ag1 + k0, Ald1);
        GLOAD_LDS16(Bg0 + k0, Bld0);
        GLOAD_LDS16(Bg1 + k0, Bld1);
        __syncthreads();

        i32x4 af[4], bf[4];
#pragma unroll
        for (int mi = 0; mi < 4; ++mi) {
            int r = wr * 64 + mi * 16 + fr;
            af[mi] = *(const i32x4*)&As[r * 64 + kc];
        }
#pragma unroll
        for (int ni = 0; ni < 4; ++ni) {
            int r = wc * 64 + ni * 16 + fr;
            bf[ni] = *(const i32x4*)&Bs[r * 64 + kc];
        }
#pragma unroll
        for (int mi = 0; mi < 4; ++mi)
#pragma unroll
            for (int ni = 0; ni < 4; ++ni)
                acc[mi][ni] = __builtin_amdgcn_mfma_i32_16x16x64_i8(
                    af[mi], bf[ni], acc[mi][ni], 0, 0, 0);
        __syncthreads();
    }

    // epilogue: C/D mapping (dtype-independent): n = lane&15, m = (lane>>4)*4 + reg
#pragma unroll
    for (int mi = 0; mi < 4; ++mi) {
#pragma unroll
        for (int ni = 0; ni < 4; ++ni) {
            long n = col0 + wc * 64 + ni * 16 + (lane & 15);
            long mbase = row0 + wr * 64 + mi * 16 + (lane >> 4) * 4;
#pragma unroll
            for (int r = 0; r < 4; ++r) {
                out[(mbase + r) * NCOLS + n] = alpha * (float)acc[mi][ni][r];
            }
        }
    }
}

// ---------------- host launch ----------------------------------------------------
extern "C" void kernel_launch(void* const* d_in, const int* in_sizes, int n_in,
                              void* d_out, int out_size, void* d_ws, size_t ws_size,
                              hipStream_t stream) {
    const float* x = (const float*)d_in[0];   // 8192 x 4096 f32
    const float* w = (const float*)d_in[1];   // 4096 x 4096 f32
    float* out = (float*)d_out;               // 8192 x 4096 f32

    uint8_t* ws = (uint8_t*)d_ws;
    signed char* Xq = (signed char*)ws;                  // i8 ternary x
    signed char* Wq = (signed char*)(ws + XQ_BYTES);     // i8 ternary w
    float* scal = (float*)(ws + SCAL_OFF);               // [delta_x, delta_w, alpha, pad]
    // partials at scal+4 (768 floats)

    k_reduce_abs<<<768, 256, 0, stream>>>(x, w, scal + 4);
    k_finalize<<<1, 256, 0, stream>>>(scal);
    k_quant<<<4096, 256, 0, stream>>>(x, (int*)Xq, scal, 0, MROWS * KDIM / 4);
    k_quant<<<2048, 256, 0, stream>>>(w, (int*)Wq, scal, 1, NCOLS * KDIM / 4);
    k_gemm<<<2048, 256, 0, stream>>>(Xq, Wq, out, scal);
}

// Round 3
// 222.669 us; speedup vs baseline: 2.0178x; 1.1824x over previous
//
#include <hip/hip_runtime.h>
#include <stdint.h>

typedef __attribute__((ext_vector_type(4))) int i32x4;

#define MROWS 8192L
#define NCOLS 4096L
#define KDIM  4096L

#define XQ_BYTES   (MROWS * KDIM)                // 33554432 (i8)
#define WQ_BYTES   (NCOLS * KDIM)                // 16777216 (i8)
#define SCAL_OFF   (XQ_BYTES + WQ_BYTES)

// ternary -> i8 {-1,0,+1}
__device__ __forceinline__ int tq_i8(float v, float delta) {
    return v > delta ? 1 : (v < -delta ? -1 : 0);
}

// ---------------- reduction: sum|x| (blocks 0..511), sum|w| (blocks 512..767) ----
__global__ __launch_bounds__(256) void k_reduce_abs(const float* __restrict__ x,
                                                    const float* __restrict__ w,
                                                    float* __restrict__ partials) {
    __shared__ float sm[256];
    int b = blockIdx.x;
    int t = threadIdx.x;
    const float4* v;
    long base;
    if (b < 512) { v = (const float4*)x; base = (long)b * 16384; }
    else         { v = (const float4*)w; base = (long)(b - 512) * 16384; }
    float s = 0.f;
    for (int i = t; i < 16384; i += 256) {
        float4 q = v[base + i];
        s += fabsf(q.x) + fabsf(q.y) + fabsf(q.z) + fabsf(q.w);
    }
    sm[t] = s;
    __syncthreads();
    for (int off = 128; off > 0; off >>= 1) {
        if (t < off) sm[t] += sm[t + off];
        __syncthreads();
    }
    if (t == 0) partials[b] = sm[0];
}

// ---------------- finalize: double-precision combine, write scalars --------------
__global__ __launch_bounds__(256) void k_finalize(float* __restrict__ scal) {
    const float* partials = scal + 4;
    __shared__ double sm[256];
    int t = threadIdx.x;

    double sx = 0.0;
    for (int i = t; i < 512; i += 256) sx += (double)partials[i];
    sm[t] = sx;
    __syncthreads();
    for (int off = 128; off > 0; off >>= 1) {
        if (t < off) sm[t] += sm[t + off];
        __syncthreads();
    }
    double SX = sm[0];
    __syncthreads();

    double sw = (double)partials[512 + t];
    sm[t] = sw;
    __syncthreads();
    for (int off = 128; off > 0; off >>= 1) {
        if (t < off) sm[t] += sm[t + off];
        __syncthreads();
    }
    if (t == 0) {
        float meanx = (float)(SX / 33554432.0);
        float meanw = (float)(sm[0] / 16777216.0);
        scal[0] = 0.1f * meanx;   // delta_x
        scal[1] = 0.05f * meanw;  // delta_w
        scal[2] = meanw;          // alpha
    }
}

// ---------------- ternarize to i8 {-1,0,1}, 4 floats -> 1 packed word ------------
__global__ __launch_bounds__(256) void k_quant(const float* __restrict__ src,
                                               int* __restrict__ dst,
                                               const float* __restrict__ scal,
                                               int scal_idx, long total4) {
    float delta = scal[scal_idx];
    long i0 = (long)blockIdx.x * 256 + threadIdx.x;
    long stride = (long)gridDim.x * 256;
    const float4* s4 = (const float4*)src;
    for (long i = i0; i < total4; i += stride) {
        float4 q = s4[i];
        int wd = (tq_i8(q.x, delta) & 0xff)
               | ((tq_i8(q.y, delta) & 0xff) << 8)
               | ((tq_i8(q.z, delta) & 0xff) << 16)
               | ((tq_i8(q.w, delta) & 0xff) << 24);
        dst[i] = wd;
    }
}

// ---------------- GEMM: out = alpha * (Xq @ Wq^T), 256x256 tile, i8, T2+T3+T4+T5 --
#define GLOAD_LDS16(g, l)                                                             \
    __builtin_amdgcn_global_load_lds((const __attribute__((address_space(1))) void*)(g), \
                                     (__attribute__((address_space(3))) void*)(l),       \
                                     16, 0, 0)

#define MFMA_I8 __builtin_amdgcn_mfma_i32_16x16x64_i8

__global__ __launch_bounds__(512, 2) void k_gemm(const signed char* __restrict__ Xq,
                                                 const signed char* __restrict__ Wq,
                                                 float* __restrict__ out,
                                                 const float* __restrict__ scal) {
    // [buf(2)][ A 256x128B | B 256x128B ] = 2 * 64 KB = 128 KB
    __shared__ __attribute__((aligned(16))) signed char lds[131072];

    const float alpha = scal[2];

    // XCD-aware bijective swizzle (512 blocks, 512 % 8 == 0, cpx = 64)
    int bid = (int)blockIdx.x;
    bid = (bid & 7) * 64 + (bid >> 3);
    int bm = bid >> 4;                 // 0..31  (M/256)
    int bn = bid & 15;                 // 0..15  (N/256)
    long row0 = (long)bm * 256;
    long col0 = (long)bn * 256;

    int t = threadIdx.x;               // 0..511
    int lane = t & 63;
    int wid = t >> 6;                  // 0..7
    int wm = wid >> 2;                 // 0..1  (M half)
    int wn = wid & 3;                  // 0..3  (N quarter)

    // ---- staging: pre-swizzled global source, linear LDS dest (T2 via m173) ----
    // chunk c = issue*512 + t : row = c>>3, slot = c&7
    // LDS[row][slot*16] must hold G[row][(slot ^ (row&7))*16]
    int srow = t >> 3;                               // 0..63 within a 64-row issue block
    int scol = ((t & 7) ^ (srow & 7)) * 16;          // swizzled source byte col
    const signed char* Asrc = Xq + (row0 + srow) * KDIM + scol;
    const signed char* Bsrc = Wq + (col0 + srow) * KDIM + scol;
    const int ldst = wid * 1024;                     // wave-uniform LDS base (+i*8192)

#define STAGE(pb, g1) do {                                                     \
    const signed char* a_ = Asrc + (long)(g1) * 128;                           \
    const signed char* b_ = Bsrc + (long)(g1) * 128;                           \
    signed char* la_ = lds + (pb) * 65536 + ldst;                              \
    signed char* lb_ = la_ + 32768;                                            \
    _Pragma("unroll")                                                          \
    for (int i_ = 0; i_ < 4; ++i_) {                                           \
        GLOAD_LDS16(a_ + (long)i_ * (64 * KDIM), la_ + i_ * 8192);             \
        GLOAD_LDS16(b_ + (long)i_ * (64 * KDIM), lb_ + i_ * 8192);             \
    } } while (0)

    // ---- fragment read addressing (swizzled ds_read side) ----
    int fr = lane & 15;                 // fragment row (A: m, B: n)
    int kc = (lane >> 4) * 16;          // k byte offset within 64-k substep
    int e = (fr & 7) << 4;              // swizzle key: row&7 == fr&7 (16-row frag stride)
    int ck0 = kc ^ e;                   // ks=0 byte col
    int ck1 = (kc + 64) ^ e;            // ks=1 byte col
    int aoff = (wm * 128 + fr) * 128;           // + pb*65536 + mi*2048 + ck
    int boff = 32768 + (wn * 64 + fr) * 128;    // + pb*65536 + ni*2048 + ck

    i32x4 acc[8][4];
#pragma unroll
    for (int i = 0; i < 8; ++i)
#pragma unroll
        for (int j = 0; j < 4; ++j)
            acc[i][j] = (i32x4){0, 0, 0, 0};

    STAGE(0, 0);   // prologue: K-tile 0 -> buf0

    for (int g = 0; g < 32; ++g) {
        int pb = g & 1;
        // B1: all waves done reading buf[pb^1] (K-tile g-1) -> safe to overwrite
        __builtin_amdgcn_s_barrier();
        if (g + 1 < 32) {
            STAGE(pb ^ 1, g + 1);                                // issue-early (full-group overlap)
            asm volatile("s_waitcnt vmcnt(8)" ::: "memory");     // K-tile g landed; g+1 in flight
        } else {
            asm volatile("s_waitcnt vmcnt(0)" ::: "memory");     // final tile drain (once)
        }
        // B2: publish "my K-tile-g stages landed" to all waves
        __builtin_amdgcn_s_barrier();
        __builtin_amdgcn_sched_barrier(0);

        const signed char* A = lds + pb * 65536 + aoff;
        const signed char* B = lds + pb * 65536 + boff;

        i32x4 a0[4][2], b0[2][2], b1[2][2];
        // ---- phase 0: A m0-3, B n0-1 ----
#pragma unroll
        for (int mi = 0; mi < 4; ++mi) {
            a0[mi][0] = *(const i32x4*)(A + mi * 2048 + ck0);
            a0[mi][1] = *(const i32x4*)(A + mi * 2048 + ck1);
        }
#pragma unroll
        for (int ni = 0; ni < 2; ++ni) {
            b0[ni][0] = *(const i32x4*)(B + ni * 2048 + ck0);
            b0[ni][1] = *(const i32x4*)(B + ni * 2048 + ck1);
        }
        __builtin_amdgcn_s_setprio(1);
#pragma unroll
        for (int mi = 0; mi < 4; ++mi)
#pragma unroll
            for (int ni = 0; ni < 2; ++ni) {
                acc[mi][ni] = MFMA_I8(a0[mi][0], b0[ni][0], acc[mi][ni], 0, 0, 0);
                acc[mi][ni] = MFMA_I8(a0[mi][1], b0[ni][1], acc[mi][ni], 0, 0, 0);
            }
        __builtin_amdgcn_s_setprio(0);
        // ---- phase 1: B n2-3 ----
#pragma unroll
        for (int ni = 0; ni < 2; ++ni) {
            b1[ni][0] = *(const i32x4*)(B + (ni + 2) * 2048 + ck0);
            b1[ni][1] = *(const i32x4*)(B + (ni + 2) * 2048 + ck1);
        }
        __builtin_amdgcn_s_setprio(1);
#pragma unroll
        for (int mi = 0; mi < 4; ++mi)
#pragma unroll
            for (int ni = 0; ni < 2; ++ni) {
                acc[mi][ni + 2] = MFMA_I8(a0[mi][0], b1[ni][0], acc[mi][ni + 2], 0, 0, 0);
                acc[mi][ni + 2] = MFMA_I8(a0[mi][1], b1[ni][1], acc[mi][ni + 2], 0, 0, 0);
            }
        __builtin_amdgcn_s_setprio(0);
        // ---- phase 2: A m4-7 ----
#pragma unroll
        for (int mi = 0; mi < 4; ++mi) {
            a0[mi][0] = *(const i32x4*)(A + (mi + 4) * 2048 + ck0);
            a0[mi][1] = *(const i32x4*)(A + (mi + 4) * 2048 + ck1);
        }
        __builtin_amdgcn_s_setprio(1);
#pragma unroll
        for (int mi = 0; mi < 4; ++mi)
#pragma unroll
            for (int ni = 0; ni < 2; ++ni) {
                acc[mi + 4][ni] = MFMA_I8(a0[mi][0], b0[ni][0], acc[mi + 4][ni], 0, 0, 0);
                acc[mi + 4][ni] = MFMA_I8(a0[mi][1], b0[ni][1], acc[mi + 4][ni], 0, 0, 0);
            }
        __builtin_amdgcn_s_setprio(0);
        // ---- phase 3: m4-7 x n2-3 ----
        __builtin_amdgcn_s_setprio(1);
#pragma unroll
        for (int mi = 0; mi < 4; ++mi)
#pragma unroll
            for (int ni = 0; ni < 2; ++ni) {
                acc[mi + 4][ni + 2] = MFMA_I8(a0[mi][0], b1[ni][0], acc[mi + 4][ni + 2], 0, 0, 0);
                acc[mi + 4][ni + 2] = MFMA_I8(a0[mi][1], b1[ni][1], acc[mi + 4][ni + 2], 0, 0, 0);
            }
        __builtin_amdgcn_s_setprio(0);
    }

    // epilogue: C/D mapping (dtype-independent): n = lane&15, m = (lane>>4)*4 + reg
#pragma unroll
    for (int mi = 0; mi < 8; ++mi) {
#pragma unroll
        for (int ni = 0; ni < 4; ++ni) {
            long col = col0 + wn * 64 + ni * 16 + (lane & 15);
            long rowb = row0 + wm * 128 + mi * 16 + (lane >> 4) * 4;
#pragma unroll
            for (int r = 0; r < 4; ++r) {
                out[(rowb + r) * NCOLS + col] = alpha * (float)acc[mi][ni][r];
            }
        }
    }
#undef STAGE
}

// ---------------- host launch ----------------------------------------------------
extern "C" void kernel_launch(void* const* d_in, const int* in_sizes, int n_in,
                              void* d_out, int out_size, void* d_ws, size_t ws_size,
                              hipStream_t stream) {
    const float* x = (const float*)d_in[0];   // 8192 x 4096 f32
    const float* w = (const float*)d_in[1];   // 4096 x 4096 f32
    float* out = (float*)d_out;               // 8192 x 4096 f32

    uint8_t* ws = (uint8_t*)d_ws;
    signed char* Xq = (signed char*)ws;                  // i8 ternary x
    signed char* Wq = (signed char*)(ws + XQ_BYTES);     // i8 ternary w
    float* scal = (float*)(ws + SCAL_OFF);               // [delta_x, delta_w, alpha, pad]
    // partials at scal+4 (768 floats)

    k_reduce_abs<<<768, 256, 0, stream>>>(x, w, scal + 4);
    k_finalize<<<1, 256, 0, stream>>>(scal);
    k_quant<<<4096, 256, 0, stream>>>(x, (int*)Xq, scal, 0, MROWS * KDIM / 4);
    k_quant<<<2048, 256, 0, stream>>>(w, (int*)Wq, scal, 1, NCOLS * KDIM / 4);
    k_gemm<<<512, 512, 0, stream>>>(Xq, Wq, out, scal);
}

// Round 4
// 164.125 us; speedup vs baseline: 2.7376x; 1.3567x over previous
//
#include <hip/hip_runtime.h>
#include <stdint.h>

typedef __attribute__((ext_vector_type(4))) int i32x4;
typedef __attribute__((ext_vector_type(8))) int i32x8;
typedef __attribute__((ext_vector_type(4))) float f32x4;

#define MROWS 8192L
#define NCOLS 4096L
#define KDIM  4096L

#define XQ_BYTES   (MROWS * KDIM / 2)            // 16777216 (fp4: 2048 B/row)
#define WQ_BYTES   (NCOLS * KDIM / 2)            // 8388608
#define SCAL_OFF   (XQ_BYTES + WQ_BYTES)

// ---------------- reduction: sum|x| (blocks 0..511), sum|w| (blocks 512..767) ----
__global__ __launch_bounds__(256) void k_reduce_abs(const float* __restrict__ x,
                                                    const float* __restrict__ w,
                                                    float* __restrict__ partials) {
    __shared__ float sm[256];
    int b = blockIdx.x;
    int t = threadIdx.x;
    const float4* v;
    long base;
    if (b < 512) { v = (const float4*)x; base = (long)b * 16384; }
    else         { v = (const float4*)w; base = (long)(b - 512) * 16384; }
    float s = 0.f;
    for (int i = t; i < 16384; i += 256) {
        float4 q = v[base + i];
        s += fabsf(q.x) + fabsf(q.y) + fabsf(q.z) + fabsf(q.w);
    }
    sm[t] = s;
    __syncthreads();
    for (int off = 128; off > 0; off >>= 1) {
        if (t < off) sm[t] += sm[t + off];
        __syncthreads();
    }
    if (t == 0) partials[b] = sm[0];
}

// ---------------- finalize: double-precision combine, write scalars --------------
__global__ __launch_bounds__(256) void k_finalize(float* __restrict__ scal) {
    const float* partials = scal + 4;
    __shared__ double sm[256];
    int t = threadIdx.x;

    double sx = 0.0;
    for (int i = t; i < 512; i += 256) sx += (double)partials[i];
    sm[t] = sx;
    __syncthreads();
    for (int off = 128; off > 0; off >>= 1) {
        if (t < off) sm[t] += sm[t + off];
        __syncthreads();
    }
    double SX = sm[0];
    __syncthreads();

    double sw = (double)partials[512 + t];
    sm[t] = sw;
    __syncthreads();
    for (int off = 128; off > 0; off >>= 1) {
        if (t < off) sm[t] += sm[t + off];
        __syncthreads();
    }
    if (t == 0) {
        float meanx = (float)(SX / 33554432.0);
        float meanw = (float)(sm[0] / 16777216.0);
        scal[0] = 0.1f * meanx;   // delta_x
        scal[1] = 0.05f * meanw;  // delta_w
        scal[2] = meanw;          // alpha
    }
}

// ---------------- ternarize to fp4 e2m1 {-1,0,1}: 8 floats -> 1 uint -------------
__device__ __forceinline__ unsigned int nib4(float v, float delta) {
    return v > delta ? 2u : (v < -delta ? 10u : 0u);   // +1=0x2, -1=0xA, 0=0x0
}

__global__ __launch_bounds__(256) void k_quant4(const float* __restrict__ src,
                                                unsigned int* __restrict__ dst,
                                                const float* __restrict__ scal,
                                                int scal_idx, long total8) {
    float delta = scal[scal_idx];
    long i0 = (long)blockIdx.x * 256 + threadIdx.x;
    long stride = (long)gridDim.x * 256;
    const float4* s4 = (const float4*)src;
    for (long i = i0; i < total8; i += stride) {
        float4 q0 = s4[2 * i];
        float4 q1 = s4[2 * i + 1];
        unsigned int wd = nib4(q0.x, delta)
                        | (nib4(q0.y, delta) << 4)
                        | (nib4(q0.z, delta) << 8)
                        | (nib4(q0.w, delta) << 12)
                        | (nib4(q1.x, delta) << 16)
                        | (nib4(q1.y, delta) << 20)
                        | (nib4(q1.z, delta) << 24)
                        | (nib4(q1.w, delta) << 28);
        dst[i] = wd;
    }
}

// ---------------- GEMM: out = alpha * (Xq @ Wq^T), fp4 MFMA K=128, 4-deep ring ---
#define GLOAD_LDS16(g, l)                                                             \
    __builtin_amdgcn_global_load_lds((const __attribute__((address_space(1))) void*)(g), \
                                     (__attribute__((address_space(3))) void*)(l),       \
                                     16, 0, 0)

// i32x4 -> i32x8 with undef high half (fp4 A/B data occupies low 4 VGPRs)
#define MK8(v) __builtin_shufflevector((v), (v), 0, 1, 2, 3, -1, -1, -1, -1)

// fp4 x fp4, scales = 1.0 (E8M0 127 in every byte)
#define MFMA4(a, b, c)                                                        \
    __builtin_amdgcn_mfma_scale_f32_16x16x128_f8f6f4(MK8(a), MK8(b), (c),     \
        4, 4, 0, 0x7F7F7F7F, 0, 0x7F7F7F7F)

__global__ __launch_bounds__(512, 2) void k_gemm(const signed char* __restrict__ Xq,
                                                 const signed char* __restrict__ Wq,
                                                 float* __restrict__ out,
                                                 const float* __restrict__ scal) {
    // ring of 4 K-tile slots: [slot][ A 256x64B | B 256x64B ] = 4 * 32 KB = 128 KB
    __shared__ __attribute__((aligned(16))) signed char lds[131072];

    const float alpha = scal[2];

    // XCD-aware bijective swizzle (512 blocks, 512 % 8 == 0, cpx = 64)
    int bid = (int)blockIdx.x;
    bid = (bid & 7) * 64 + (bid >> 3);
    int bm = bid >> 4;                 // 0..31  (M/256)
    int bn = bid & 15;                 // 0..15  (N/256)
    long row0 = (long)bm * 256;
    long col0 = (long)bn * 256;

    int t = threadIdx.x;               // 0..511
    int lane = t & 63;
    int wid = t >> 6;                  // 0..7
    int wm = wid >> 2;                 // 0..1  (M half)
    int wn = wid & 3;                  // 0..3  (N quarter)

    // ---- staging: pre-swizzled global source, linear LDS dest ----
    // LDS[row][slot*16] = G[row][(slot ^ ((row>>1)&3))*16]; row = i*128 + (t>>2)
    int srow = t >> 2;                               // 0..127
    int scol = ((t & 3) ^ ((t >> 3) & 3)) * 16;      // swizzled source byte col
    const signed char* Asrc = Xq + (row0 + srow) * 2048 + scol;
    const signed char* Bsrc = Wq + (col0 + srow) * 2048 + scol;
    const int ldst = wid * 1024;                     // wave-uniform LDS base

#define STAGE(slot, g1) do {                                                   \
    const signed char* a_ = Asrc + (long)(g1) * 64;                            \
    const signed char* b_ = Bsrc + (long)(g1) * 64;                            \
    signed char* la_ = lds + (slot) * 32768 + ldst;                            \
    signed char* lb_ = la_ + 16384;                                            \
    GLOAD_LDS16(a_, la_);                                                      \
    GLOAD_LDS16(a_ + 128L * 2048, la_ + 8192);                                 \
    GLOAD_LDS16(b_, lb_);                                                      \
    GLOAD_LDS16(b_ + 128L * 2048, lb_ + 8192);                                 \
} while (0)

    // ---- fragment read addressing (swizzled ds_read side) ----
    int fr = lane & 15;                                    // fragment row
    int ck = (((lane >> 4) ^ ((fr >> 1) & 3)) << 4);       // swizzled k-byte col
    int aoff = (wm * 128 + fr) * 64;                       // + slot*32768 + mi*1024 + ck
    int boff = 16384 + (wn * 64 + fr) * 64;                // + slot*32768 + ni*1024 + ck

    f32x4 acc[8][4];
#pragma unroll
    for (int i = 0; i < 8; ++i)
#pragma unroll
        for (int j = 0; j < 4; ++j)
            acc[i][j] = (f32x4){0.f, 0.f, 0.f, 0.f};

    // prologue: stage K-tiles 0,1,2 into slots 0,1,2 (12 loads in flight)
    STAGE(0, 0);
    STAGE(1, 1);
    STAGE(2, 2);

    for (int g = 0; g < 32; ++g) {
        int slot = g & 3;
        // B1: all waves done reading slot (g+3)&3's old contents (tile g-1)
        __builtin_amdgcn_s_barrier();
        if (g < 29) {
            STAGE((g + 3) & 3, g + 3);
            asm volatile("s_waitcnt vmcnt(12)" ::: "memory");  // tile g landed; g+1..g+3 in flight
        } else if (g == 29) {
            asm volatile("s_waitcnt vmcnt(8)" ::: "memory");
        } else if (g == 30) {
            asm volatile("s_waitcnt vmcnt(4)" ::: "memory");
        } else {
            asm volatile("s_waitcnt vmcnt(0)" ::: "memory");
        }
        // B2: publish "tile g fully landed" to all waves
        __builtin_amdgcn_s_barrier();
        __builtin_amdgcn_sched_barrier(0);

        const signed char* A = lds + slot * 32768 + aoff;
        const signed char* B = lds + slot * 32768 + boff;

        i32x4 a0, a1, a2, a3, b0, b1, b2, b3;
        // ---- phase 0: A m0-3, B n0-1 ----
        a0 = *(const i32x4*)(A + 0 * 1024 + ck);
        a1 = *(const i32x4*)(A + 1 * 1024 + ck);
        a2 = *(const i32x4*)(A + 2 * 1024 + ck);
        a3 = *(const i32x4*)(A + 3 * 1024 + ck);
        b0 = *(const i32x4*)(B + 0 * 1024 + ck);
        b1 = *(const i32x4*)(B + 1 * 1024 + ck);
        __builtin_amdgcn_s_setprio(1);
        acc[0][0] = MFMA4(a0, b0, acc[0][0]);
        acc[1][0] = MFMA4(a1, b0, acc[1][0]);
        acc[2][0] = MFMA4(a2, b0, acc[2][0]);
        acc[3][0] = MFMA4(a3, b0, acc[3][0]);
        acc[0][1] = MFMA4(a0, b1, acc[0][1]);
        acc[1][1] = MFMA4(a1, b1, acc[1][1]);
        acc[2][1] = MFMA4(a2, b1, acc[2][1]);
        acc[3][1] = MFMA4(a3, b1, acc[3][1]);
        __builtin_amdgcn_s_setprio(0);
        // ---- phase 1: B n2-3 ----
        b2 = *(const i32x4*)(B + 2 * 1024 + ck);
        b3 = *(const i32x4*)(B + 3 * 1024 + ck);
        __builtin_amdgcn_s_setprio(1);
        acc[0][2] = MFMA4(a0, b2, acc[0][2]);
        acc[1][2] = MFMA4(a1, b2, acc[1][2]);
        acc[2][2] = MFMA4(a2, b2, acc[2][2]);
        acc[3][2] = MFMA4(a3, b2, acc[3][2]);
        acc[0][3] = MFMA4(a0, b3, acc[0][3]);
        acc[1][3] = MFMA4(a1, b3, acc[1][3]);
        acc[2][3] = MFMA4(a2, b3, acc[2][3]);
        acc[3][3] = MFMA4(a3, b3, acc[3][3]);
        __builtin_amdgcn_s_setprio(0);
        // ---- phase 2: A m4-7, B n0-1 ----
        a0 = *(const i32x4*)(A + 4 * 1024 + ck);
        a1 = *(const i32x4*)(A + 5 * 1024 + ck);
        a2 = *(const i32x4*)(A + 6 * 1024 + ck);
        a3 = *(const i32x4*)(A + 7 * 1024 + ck);
        __builtin_amdgcn_s_setprio(1);
        acc[4][0] = MFMA4(a0, b0, acc[4][0]);
        acc[5][0] = MFMA4(a1, b0, acc[5][0]);
        acc[6][0] = MFMA4(a2, b0, acc[6][0]);
        acc[7][0] = MFMA4(a3, b0, acc[7][0]);
        acc[4][1] = MFMA4(a0, b1, acc[4][1]);
        acc[5][1] = MFMA4(a1, b1, acc[5][1]);
        acc[6][1] = MFMA4(a2, b1, acc[6][1]);
        acc[7][1] = MFMA4(a3, b1, acc[7][1]);
        __builtin_amdgcn_s_setprio(0);
        // ---- phase 3: A m4-7, B n2-3 ----
        __builtin_amdgcn_s_setprio(1);
        acc[4][2] = MFMA4(a0, b2, acc[4][2]);
        acc[5][2] = MFMA4(a1, b2, acc[5][2]);
        acc[6][2] = MFMA4(a2, b2, acc[6][2]);
        acc[7][2] = MFMA4(a3, b2, acc[7][2]);
        acc[4][3] = MFMA4(a0, b3, acc[4][3]);
        acc[5][3] = MFMA4(a1, b3, acc[5][3]);
        acc[6][3] = MFMA4(a2, b3, acc[6][3]);
        acc[7][3] = MFMA4(a3, b3, acc[7][3]);
        __builtin_amdgcn_s_setprio(0);
    }

    // epilogue: C/D mapping (dtype-independent): n = lane&15, m = (lane>>4)*4 + reg
#pragma unroll
    for (int mi = 0; mi < 8; ++mi) {
#pragma unroll
        for (int ni = 0; ni < 4; ++ni) {
            long col = col0 + wn * 64 + ni * 16 + (lane & 15);
            long rowb = row0 + wm * 128 + mi * 16 + (lane >> 4) * 4;
#pragma unroll
            for (int r = 0; r < 4; ++r) {
                out[(rowb + r) * NCOLS + col] = alpha * acc[mi][ni][r];
            }
        }
    }
#undef STAGE
}

// ---------------- host launch ----------------------------------------------------
extern "C" void kernel_launch(void* const* d_in, const int* in_sizes, int n_in,
                              void* d_out, int out_size, void* d_ws, size_t ws_size,
                              hipStream_t stream) {
    const float* x = (const float*)d_in[0];   // 8192 x 4096 f32
    const float* w = (const float*)d_in[1];   // 4096 x 4096 f32
    float* out = (float*)d_out;               // 8192 x 4096 f32

    uint8_t* ws = (uint8_t*)d_ws;
    signed char* Xq = (signed char*)ws;                  // fp4 ternary x (16 MB)
    signed char* Wq = (signed char*)(ws + XQ_BYTES);     // fp4 ternary w (8 MB)
    float* scal = (float*)(ws + SCAL_OFF);               // [delta_x, delta_w, alpha, pad]
    // partials at scal+4 (768 floats)

    k_reduce_abs<<<768, 256, 0, stream>>>(x, w, scal + 4);
    k_finalize<<<1, 256, 0, stream>>>(scal);
    k_quant4<<<2048, 256, 0, stream>>>(x, (unsigned int*)Xq, scal, 0, MROWS * KDIM / 8);
    k_quant4<<<1024, 256, 0, stream>>>(w, (unsigned int*)Wq, scal, 1, NCOLS * KDIM / 8);
    k_gemm<<<512, 512, 0, stream>>>(Xq, Wq, out, scal);
}

// Round 5
// 161.662 us; speedup vs baseline: 2.7793x; 1.0152x over previous
//
#include <hip/hip_runtime.h>
#include <stdint.h>

typedef __attribute__((ext_vector_type(4))) int i32x4;
typedef __attribute__((ext_vector_type(4))) float f32x4;

#define MROWS 8192L
#define NCOLS 4096L
#define KDIM  4096L

#define XQ_BYTES   (MROWS * KDIM / 2)            // 16777216 (fp4: 2048 B/row)
#define WQ_BYTES   (NCOLS * KDIM / 2)            // 8388608
#define SCAL_OFF   (XQ_BYTES + WQ_BYTES)

// ---------------- reduction: sum|x| (blocks 0..511), sum|w| (blocks 512..767) ----
__global__ __launch_bounds__(256) void k_reduce_abs(const float* __restrict__ x,
                                                    const float* __restrict__ w,
                                                    float* __restrict__ partials) {
    __shared__ float sm[256];
    int b = blockIdx.x;
    int t = threadIdx.x;
    const float4* v;
    long base;
    if (b < 512) { v = (const float4*)x; base = (long)b * 16384; }
    else         { v = (const float4*)w; base = (long)(b - 512) * 16384; }
    float s = 0.f;
    for (int i = t; i < 16384; i += 256) {
        float4 q = v[base + i];
        s += fabsf(q.x) + fabsf(q.y) + fabsf(q.z) + fabsf(q.w);
    }
    sm[t] = s;
    __syncthreads();
    for (int off = 128; off > 0; off >>= 1) {
        if (t < off) sm[t] += sm[t + off];
        __syncthreads();
    }
    if (t == 0) partials[b] = sm[0];
}

// ---------------- finalize: double-precision combine, write scalars --------------
__global__ __launch_bounds__(256) void k_finalize(float* __restrict__ scal) {
    const float* partials = scal + 4;
    __shared__ double sm[256];
    int t = threadIdx.x;

    double sx = 0.0;
    for (int i = t; i < 512; i += 256) sx += (double)partials[i];
    sm[t] = sx;
    __syncthreads();
    for (int off = 128; off > 0; off >>= 1) {
        if (t < off) sm[t] += sm[t + off];
        __syncthreads();
    }
    double SX = sm[0];
    __syncthreads();

    double sw = (double)partials[512 + t];
    sm[t] = sw;
    __syncthreads();
    for (int off = 128; off > 0; off >>= 1) {
        if (t < off) sm[t] += sm[t + off];
        __syncthreads();
    }
    if (t == 0) {
        float meanx = (float)(SX / 33554432.0);
        float meanw = (float)(sm[0] / 16777216.0);
        scal[0] = 0.1f * meanx;   // delta_x
        scal[1] = 0.05f * meanw;  // delta_w
        scal[2] = meanw;          // alpha
    }
}

// ---------------- ternarize to fp4 e2m1 {-1,0,1}: 8 floats -> 1 uint -------------
__device__ __forceinline__ unsigned int nib4(float v, float delta) {
    return v > delta ? 2u : (v < -delta ? 10u : 0u);   // +1=0x2, -1=0xA, 0=0x0
}

// merged x+w quantization (blocks [0,2048): x, [2048,3072): w)
__global__ __launch_bounds__(256) void k_quant4(const float* __restrict__ x,
                                                const float* __restrict__ w,
                                                unsigned int* __restrict__ xq,
                                                unsigned int* __restrict__ wq,
                                                const float* __restrict__ scal) {
    int b = blockIdx.x;
    const float* src;
    unsigned int* dst;
    float delta;
    long i0, stride, total8;
    if (b < 2048) {
        src = x; dst = xq; delta = scal[0];
        i0 = (long)b * 256 + threadIdx.x; stride = 2048L * 256; total8 = MROWS * KDIM / 8;
    } else {
        src = w; dst = wq; delta = scal[1];
        i0 = (long)(b - 2048) * 256 + threadIdx.x; stride = 1024L * 256; total8 = NCOLS * KDIM / 8;
    }
    const float4* s4 = (const float4*)src;
    for (long i = i0; i < total8; i += stride) {
        float4 q0 = s4[2 * i];
        float4 q1 = s4[2 * i + 1];
        unsigned int wd = nib4(q0.x, delta)
                        | (nib4(q0.y, delta) << 4)
                        | (nib4(q0.z, delta) << 8)
                        | (nib4(q0.w, delta) << 12)
                        | (nib4(q1.x, delta) << 16)
                        | (nib4(q1.y, delta) << 20)
                        | (nib4(q1.z, delta) << 24)
                        | (nib4(q1.w, delta) << 28);
        dst[i] = wd;
    }
}

// ---------------- GEMM: out = alpha * (Xq @ Wq^T), fp4 K=128, 4-ring, 4-phase ----
#define GLOAD_LDS16(g, l)                                                             \
    __builtin_amdgcn_global_load_lds((const __attribute__((address_space(1))) void*)(g), \
                                     (__attribute__((address_space(3))) void*)(l),       \
                                     16, 0, 0)

// i32x4 -> i32x8 with undef high half (fp4 A/B data occupies low 4 VGPRs)
#define MK8(v) __builtin_shufflevector((v), (v), 0, 1, 2, 3, -1, -1, -1, -1)

// fp4 x fp4, scales = 1.0 (E8M0 127 in every byte)
#define MFMA4(a, b, c)                                                        \
    __builtin_amdgcn_mfma_scale_f32_16x16x128_f8f6f4(MK8(a), MK8(b), (c),     \
        4, 4, 0, 0x7F7F7F7F, 0, 0x7F7F7F7F)

#define PHASE_PRE()  do {                                   \
    __builtin_amdgcn_s_barrier();                           \
    asm volatile("s_waitcnt lgkmcnt(0)" ::: "memory");      \
    __builtin_amdgcn_sched_barrier(0);                      \
    __builtin_amdgcn_s_setprio(1); } while (0)
#define PHASE_POST() do {                                   \
    __builtin_amdgcn_s_setprio(0);                          \
    __builtin_amdgcn_s_barrier(); } while (0)

__global__ __launch_bounds__(512, 2) void k_gemm(const signed char* __restrict__ Xq,
                                                 const signed char* __restrict__ Wq,
                                                 float* __restrict__ out,
                                                 const float* __restrict__ scal) {
    // ring of 4 K-tile slots: [slot][ A 256x64B | B 256x64B ] = 4 * 32 KB = 128 KB
    __shared__ __attribute__((aligned(16))) signed char lds[131072];

    const float alpha = scal[2];

    // XCD-aware bijective swizzle (512 blocks, 512 % 8 == 0, cpx = 64)
    int bid = (int)blockIdx.x;
    bid = (bid & 7) * 64 + (bid >> 3);
    int bm = bid >> 4;                 // 0..31  (M/256)
    int bn = bid & 15;                 // 0..15  (N/256)
    long row0 = (long)bm * 256;
    long col0 = (long)bn * 256;

    int t = threadIdx.x;               // 0..511
    int lane = t & 63;
    int wid = t >> 6;                  // 0..7
    int wm = wid >> 2;                 // 0..1  (M half)
    int wn = wid & 3;                  // 0..3  (N quarter)

    // ---- staging: pre-swizzled global source, linear LDS dest ----
    // LDS[row][slot*16] = G[row][(slot ^ ((row>>1)&3))*16]; row = i*128 + (t>>2)
    int srow = t >> 2;                               // 0..127
    int scol = ((t & 3) ^ ((t >> 3) & 3)) * 16;      // swizzled source byte col
    const signed char* Asrc = Xq + (row0 + srow) * 2048 + scol;
    const signed char* Bsrc = Wq + (col0 + srow) * 2048 + scol;
    const int ldst = wid * 1024;                     // wave-uniform LDS base

    // full-slot stage (prologue only)
#define STAGE(slot, g1) do {                                                   \
    const signed char* a_ = Asrc + (long)(g1) * 64;                            \
    const signed char* b_ = Bsrc + (long)(g1) * 64;                            \
    signed char* la_ = lds + (slot) * 32768 + ldst;                            \
    signed char* lb_ = la_ + 16384;                                            \
    GLOAD_LDS16(a_, la_);                                                      \
    GLOAD_LDS16(a_ + 128L * 2048, la_ + 8192);                                 \
    GLOAD_LDS16(b_, lb_);                                                      \
    GLOAD_LDS16(b_ + 128L * 2048, lb_ + 8192);                                 \
} while (0)

    // ---- fragment read addressing (swizzled ds_read side) ----
    int fr = lane & 15;                                    // fragment row
    int ck = (((lane >> 4) ^ ((fr >> 1) & 3)) << 4);       // swizzled k-byte col
    int aoff = (wm * 128 + fr) * 64;                       // + slot*32768 + mi*1024 + ck
    int boff = 16384 + (wn * 64 + fr) * 64;                // + slot*32768 + ni*1024 + ck

    f32x4 acc[8][4];
#pragma unroll
    for (int i = 0; i < 8; ++i)
#pragma unroll
        for (int j = 0; j < 4; ++j)
            acc[i][j] = (f32x4){0.f, 0.f, 0.f, 0.f};

    // prologue: stage K-tiles 0,1,2 into slots 0,1,2 (12 loads in flight)
    STAGE(0, 0);
    STAGE(1, 1);
    STAGE(2, 2);

    for (int g = 0; g < 32; ++g) {
        int slot = g & 3;
        // ---- tile top: certify tile g landed; publish to all waves ----
        if (g <= 29) {
            asm volatile("s_waitcnt vmcnt(8)" ::: "memory");
        } else if (g == 30) {
            asm volatile("s_waitcnt vmcnt(4)" ::: "memory");
        } else {
            asm volatile("s_waitcnt vmcnt(0)" ::: "memory");
        }
        __builtin_amdgcn_s_barrier();
        __builtin_amdgcn_sched_barrier(0);

        const signed char* A = lds + slot * 32768 + aoff;
        const signed char* B = lds + slot * 32768 + boff;
        bool st = (g <= 28);
        const signed char* a3_ = Asrc + (long)(g + 3) * 64;
        const signed char* b3_ = Bsrc + (long)(g + 3) * 64;
        signed char* la3_ = lds + ((g + 3) & 3) * 32768 + ldst;
        signed char* lb3_ = la3_ + 16384;

        i32x4 a0, a1, a2, a3, b0, b1, b2, b3;
        // ---- phase 0: reads a0-3, b0-1 | stage chunk 0 | MFMA m0-3 x n0-1 ----
        a0 = *(const i32x4*)(A + 0 * 1024 + ck);
        a1 = *(const i32x4*)(A + 1 * 1024 + ck);
        a2 = *(const i32x4*)(A + 2 * 1024 + ck);
        a3 = *(const i32x4*)(A + 3 * 1024 + ck);
        b0 = *(const i32x4*)(B + 0 * 1024 + ck);
        b1 = *(const i32x4*)(B + 1 * 1024 + ck);
        if (st) GLOAD_LDS16(a3_, la3_);
        PHASE_PRE();
        acc[0][0] = MFMA4(a0, b0, acc[0][0]);
        acc[1][0] = MFMA4(a1, b0, acc[1][0]);
        acc[2][0] = MFMA4(a2, b0, acc[2][0]);
        acc[3][0] = MFMA4(a3, b0, acc[3][0]);
        acc[0][1] = MFMA4(a0, b1, acc[0][1]);
        acc[1][1] = MFMA4(a1, b1, acc[1][1]);
        acc[2][1] = MFMA4(a2, b1, acc[2][1]);
        acc[3][1] = MFMA4(a3, b1, acc[3][1]);
        PHASE_POST();
        // ---- phase 1: reads b2-3 | stage chunk 1 | MFMA m0-3 x n2-3 ----
        b2 = *(const i32x4*)(B + 2 * 1024 + ck);
        b3 = *(const i32x4*)(B + 3 * 1024 + ck);
        if (st) GLOAD_LDS16(a3_ + 128L * 2048, la3_ + 8192);
        PHASE_PRE();
        acc[0][2] = MFMA4(a0, b2, acc[0][2]);
        acc[1][2] = MFMA4(a1, b2, acc[1][2]);
        acc[2][2] = MFMA4(a2, b2, acc[2][2]);
        acc[3][2] = MFMA4(a3, b2, acc[3][2]);
        acc[0][3] = MFMA4(a0, b3, acc[0][3]);
        acc[1][3] = MFMA4(a1, b3, acc[1][3]);
        acc[2][3] = MFMA4(a2, b3, acc[2][3]);
        acc[3][3] = MFMA4(a3, b3, acc[3][3]);
        PHASE_POST();
        // ---- phase 2: reads a4-7 | stage chunk 2 | MFMA m4-7 x n0-1 ----
        a0 = *(const i32x4*)(A + 4 * 1024 + ck);
        a1 = *(const i32x4*)(A + 5 * 1024 + ck);
        a2 = *(const i32x4*)(A + 6 * 1024 + ck);
        a3 = *(const i32x4*)(A + 7 * 1024 + ck);
        if (st) GLOAD_LDS16(b3_, lb3_);
        PHASE_PRE();
        acc[4][0] = MFMA4(a0, b0, acc[4][0]);
        acc[5][0] = MFMA4(a1, b0, acc[5][0]);
        acc[6][0] = MFMA4(a2, b0, acc[6][0]);
        acc[7][0] = MFMA4(a3, b0, acc[7][0]);
        acc[4][1] = MFMA4(a0, b1, acc[4][1]);
        acc[5][1] = MFMA4(a1, b1, acc[5][1]);
        acc[6][1] = MFMA4(a2, b1, acc[6][1]);
        acc[7][1] = MFMA4(a3, b1, acc[7][1]);
        PHASE_POST();
        // ---- phase 3: no reads | stage chunk 3 | MFMA m4-7 x n2-3 ----
        if (st) GLOAD_LDS16(b3_ + 128L * 2048, lb3_ + 8192);
        PHASE_PRE();
        acc[4][2] = MFMA4(a0, b2, acc[4][2]);
        acc[5][2] = MFMA4(a1, b2, acc[5][2]);
        acc[6][2] = MFMA4(a2, b2, acc[6][2]);
        acc[7][2] = MFMA4(a3, b2, acc[7][2]);
        acc[4][3] = MFMA4(a0, b3, acc[4][3]);
        acc[5][3] = MFMA4(a1, b3, acc[5][3]);
        acc[6][3] = MFMA4(a2, b3, acc[6][3]);
        acc[7][3] = MFMA4(a3, b3, acc[7][3]);
        __builtin_amdgcn_s_setprio(0);
        // trailing barrier of phase 3 = next tile-top barrier
    }

    // epilogue: C/D mapping (dtype-independent): n = lane&15, m = (lane>>4)*4 + reg
#pragma unroll
    for (int mi = 0; mi < 8; ++mi) {
#pragma unroll
        for (int ni = 0; ni < 4; ++ni) {
            long col = col0 + wn * 64 + ni * 16 + (lane & 15);
            long rowb = row0 + wm * 128 + mi * 16 + (lane >> 4) * 4;
#pragma unroll
            for (int r = 0; r < 4; ++r) {
                out[(rowb + r) * NCOLS + col] = alpha * acc[mi][ni][r];
            }
        }
    }
#undef STAGE
}

// ---------------- host launch ----------------------------------------------------
extern "C" void kernel_launch(void* const* d_in, const int* in_sizes, int n_in,
                              void* d_out, int out_size, void* d_ws, size_t ws_size,
                              hipStream_t stream) {
    const float* x = (const float*)d_in[0];   // 8192 x 4096 f32
    const float* w = (const float*)d_in[1];   // 4096 x 4096 f32
    float* out = (float*)d_out;               // 8192 x 4096 f32

    uint8_t* ws = (uint8_t*)d_ws;
    signed char* Xq = (signed char*)ws;                  // fp4 ternary x (16 MB)
    signed char* Wq = (signed char*)(ws + XQ_BYTES);     // fp4 ternary w (8 MB)
    float* scal = (float*)(ws + SCAL_OFF);               // [delta_x, delta_w, alpha, pad]
    // partials at scal+4 (768 floats)

    k_reduce_abs<<<768, 256, 0, stream>>>(x, w, scal + 4);
    k_finalize<<<1, 256, 0, stream>>>(scal);
    k_quant4<<<3072, 256, 0, stream>>>(x, w, (unsigned int*)Xq, (unsigned int*)Wq, scal);
    k_gemm<<<512, 512, 0, stream>>>(Xq, Wq, out, scal);
}